// Round 4
// baseline (208.379 us; speedup 1.0000x reference)
//
#include <hip/hip_runtime.h>
#include <hip/hip_bf16.h>
#include <math.h>

// TopicRouter, single fused kernel:
//  logits[B,8] = h @ gate_w^T + b, plus per-row top-2 + softmax, one pass.
//  HBM-bound (96 MB of h).
//  R3/R4: gate weights live in 24 KB of LDS (loaded once per block, read via
//  one base reg + offset: immediates, conflict-free lane-consecutive
//  ds_read_b128). This frees ~96 VGPRs -> wave fits in 128 VGPR ->
//  __launch_bounds__(256,4) = 4 waves/SIMD, 16 waves/CU — double the TLP of
//  the register-gate version (which was capped at 2 waves/SIMD and measured
//  ~3.4 TB/s vs 6.3 achievable; fills at 9% occupancy hit 6.8 TB/s, so
//  streaming isn't the limit — thin TLP is the suspect).
//  h stays in registers with depth-1 prefetch (cv/nv, 48 VGPRs).
//  NOTE: this is NOT the old failed (256,4) variant — that kept gate in
//  registers AND staged h in LDS (guaranteed spill). Here register budget
//  ~110-125 < 128, no spill.
//  Top-2 fused in-register after the wave reduce (lax.top_k tie semantics:
//  strict >, lower index wins ties).

constexpr int D  = 768;
constexpr int E  = 8;
constexpr int D4 = D / 4;          // 192 float4 per row
constexpr int BLOCK  = 256;        // 4 waves
constexpr int GRID_A = 1024;       // 4 blocks/CU on 256 CUs; 4096 waves -> 4 pairs/wave

__device__ __forceinline__ float dot4acc(float4 a, float4 b, float acc) {
    acc = fmaf(a.x, b.x, acc);
    acc = fmaf(a.y, b.y, acc);
    acc = fmaf(a.z, b.z, acc);
    acc = fmaf(a.w, b.w, acc);
    return acc;
}

// Reduce a[8] (per-expert partials) across 64 lanes.
// Returns: this lane's total for expert e = bitrev3(lane&7).
__device__ __forceinline__ float wave_reduce8(float a[8], int lane) {
    {   // xor 1: 8 -> 4 values
        const bool hi = lane & 1;
#pragma unroll
        for (int j = 0; j < 4; ++j) {
            float send = hi ? a[j] : a[j + 4];
            float recv = __shfl_xor(send, 1, 64);
            float keep = hi ? a[j + 4] : a[j];
            a[j] = keep + recv;
        }
    }
    {   // xor 2: 4 -> 2
        const bool hi = lane & 2;
#pragma unroll
        for (int j = 0; j < 2; ++j) {
            float send = hi ? a[j] : a[j + 2];
            float recv = __shfl_xor(send, 2, 64);
            float keep = hi ? a[j + 2] : a[j];
            a[j] = keep + recv;
        }
    }
    {   // xor 4: 2 -> 1
        const bool hi = lane & 4;
        float send = hi ? a[0] : a[1];
        float recv = __shfl_xor(send, 4, 64);
        float keep = hi ? a[1] : a[0];
        a[0] = keep + recv;
    }
    float v = a[0];
    v += __shfl_xor(v, 8, 64);
    v += __shfl_xor(v, 16, 64);
    v += __shfl_xor(v, 32, 64);
    return v;
}

__device__ __forceinline__ void load_pair(float4 dst[6], const float4* __restrict__ h4,
                                          int pair, int lane) {
    const float4* hp = h4 + (size_t)pair * (2 * D4) + lane;
#pragma unroll
    for (int c = 0; c < 3; ++c) dst[c]     = hp[c * 64];        // row 2p
#pragma unroll
    for (int c = 0; c < 3; ++c) dst[3 + c] = hp[D4 + c * 64];   // row 2p+1
}

__global__ __launch_bounds__(BLOCK, 4)
void router_fused_kernel(const float* __restrict__ h,
                         const float* __restrict__ gate_w,
                         const float* __restrict__ gate_b,
                         float* __restrict__ out_idx,
                         float* __restrict__ out_w,
                         float* __restrict__ out_logits,
                         int B) {
    const int tid    = threadIdx.x;
    const int lane   = tid & 63;
    const int wave   = tid >> 6;
    const int gwave  = blockIdx.x * (BLOCK / 64) + wave;
    const int nwaves = gridDim.x * (BLOCK / 64);

    const int l3 = lane & 7;
    const int e_lane = ((l3 & 1) << 2) | (l3 & 2) | ((l3 >> 2) & 1);  // bitrev3
    const float bias = gate_b[e_lane];

    // Gate weights in LDS: [E][D4] float4 = 24 KB, loaded cooperatively once.
    // Lane reads gsh[e*D4 + c*64 + lane]: lane-consecutive 16 B -> conflict-free.
    __shared__ float4 gsh[E * D4];
    const float4* gw4 = (const float4*)gate_w;
#pragma unroll
    for (int i = 0; i < (E * D4) / BLOCK; ++i)
        gsh[i * BLOCK + tid] = gw4[i * BLOCK + tid];
    __syncthreads();

    const float4* h4 = (const float4*)h;
    const int npairs = B >> 1;

    int p = gwave;
    if (p >= npairs) return;

    float4 cv[6];
    load_pair(cv, h4, p, lane);      // prime the pipeline

    while (true) {
        const int pn = p + nwaves;
        const bool more = (pn < npairs);   // wave-uniform branch

        float4 nv[6];
        if (more) load_pair(nv, h4, pn, lane);   // in flight during compute

        float acc0[E], acc1[E];
#pragma unroll
        for (int e = 0; e < E; ++e) { acc0[e] = 0.0f; acc1[e] = 0.0f; }

#pragma unroll
        for (int c = 0; c < 3; ++c) {
#pragma unroll
            for (int e = 0; e < E; ++e) {
                float4 g = gsh[e * D4 + c * 64 + lane];
                acc0[e] = dot4acc(cv[c],     g, acc0[e]);
                acc1[e] = dot4acc(cv[3 + c], g, acc1[e]);
            }
        }

        float va = wave_reduce8(acc0, lane) + bias;
        float vb = wave_reduce8(acc1, lane) + bias;

        // Even 8-lane groups handle row 2p, odd groups row 2p+1.
        float v = (lane & 8) ? vb : va;

        // Lanes 0..15 write both rows' logits as one contiguous 64 B chunk.
        if (lane < 16) out_logits[(size_t)p * 16 + (lane & 8) + e_lane] = v;

        // Fused top-2 within each 8-lane group. Each lane holds (v, e_lane);
        // merge sorted top-2 pairs over xor 1,2,4. Comparator matches
        // lax.top_k: strict > on value, lower index wins ties.
        float t0 = v;          int x0 = e_lane;
        float t1 = -INFINITY;  int x1 = E;      // sentinel
#pragma unroll
        for (int m = 1; m <= 4; m <<= 1) {
            float w0 = __shfl_xor(t0, m, 64);
            int   j0 = __shfl_xor(x0, m, 64);
            float w1 = __shfl_xor(t1, m, 64);
            int   j1 = __shfl_xor(x1, m, 64);
            bool aFirst = (t0 > w0) || (t0 == w0 && x0 < j0);
            float f0  = aFirst ? t0 : w0;
            int   fi0 = aFirst ? x0 : j0;
            float losT = aFirst ? w0 : t0;   // loser's first
            int   losI = aFirst ? j0 : x0;
            float winT = aFirst ? t1 : w1;   // winner's second
            int   winI = aFirst ? x1 : j1;
            bool sWin = (winT > losT) || (winT == losT && winI < losI);
            float f1  = sWin ? winT : losT;
            int   fi1 = sWin ? winI : losI;
            t0 = f0; x0 = fi0; t1 = f1; x1 = fi1;
        }

        // Lane 0 writes row 2p, lane 8 writes row 2p+1.
        if ((lane & 7) == 0 && lane < 16) {
            float tt = expf(t1 - t0);
            float w0_ = 1.0f / (1.0f + tt);
            float w1_ = tt * w0_;
            const int row = 2 * p + (lane >> 3);
            ((float2*)out_idx)[row] = make_float2((float)x0, (float)x1);
            ((float2*)out_w)[row]   = make_float2(w0_, w1_);
        }

        if (!more) break;
#pragma unroll
        for (int i = 0; i < 6; ++i) cv[i] = nv[i];
        p = pn;
    }
}

extern "C" void kernel_launch(void* const* d_in, const int* in_sizes, int n_in,
                              void* d_out, int out_size, void* d_ws, size_t ws_size,
                              hipStream_t stream) {
    const float* h      = (const float*)d_in[0];
    const float* gate_w = (const float*)d_in[1];
    const float* gate_b = (const float*)d_in[2];

    const int B = in_sizes[0] / D;   // 32768

    float* out        = (float*)d_out;
    float* out_idx    = out;                       // [B,2] indices as float
    float* out_w      = out + (size_t)B * 2;       // [B,2] weights
    float* out_logits = out + (size_t)B * 4;       // [B,8] logits

    router_fused_kernel<<<dim3(GRID_A), dim3(BLOCK), 0, stream>>>(
        h, gate_w, gate_b, out_idx, out_w, out_logits, B);
}

// Round 5
// 187.417 us; speedup vs baseline: 1.1118x; 1.1118x over previous
//
#include <hip/hip_runtime.h>
#include <hip/hip_bf16.h>
#include <math.h>

// TopicRouter, single fused kernel:
//  logits[B,8] = h @ gate_w^T + b, plus per-row top-2 + softmax, one pass.
//  HBM-bound (96 MB of h).
//
//  R5: ONE ROW PER WAVE + LDS gate, sized to fit the compiler's 64-VGPR
//  occupancy target. R4 (row-pair + LDS gate) spilled: compiler chose 64
//  VGPRs for max occupancy, pipeline buffers (90+ regs live) went to
//  scratch -> 151 MB spill writes + 56 MB reloads (rocprof WRITE_SIZE),
//  104 us. Halving per-wave state (cv 12 + nv 12 + acc 8 + misc ~= 50 regs)
//  fits 64 with room; no spill possible.
//  Gate stays in 24 KB LDS (loaded once per block, lane-consecutive
//  conflict-free ds_read_b128); LDS caps residency at 6 blocks/CU =
//  24 waves/CU (75% occupancy) -> 3x the TLP of the old register-gate
//  version (2 waves/SIMD, 3.4 TB/s). h loads stay registers with depth-1
//  prefetch.
//  Top-2 fused in-register after the wave reduce (lax.top_k tie semantics:
//  strict >, lower index wins ties).

constexpr int D  = 768;
constexpr int E  = 8;
constexpr int D4 = D / 4;          // 192 float4 per row
constexpr int BLOCK  = 256;        // 4 waves
constexpr int GRID_A = 1536;       // 6 blocks/CU (LDS-capped) x 256 CU

__device__ __forceinline__ float dot4acc(float4 a, float4 b, float acc) {
    acc = fmaf(a.x, b.x, acc);
    acc = fmaf(a.y, b.y, acc);
    acc = fmaf(a.z, b.z, acc);
    acc = fmaf(a.w, b.w, acc);
    return acc;
}

// Reduce a[8] (per-expert partials) across 64 lanes.
// Returns: this lane's total for expert e = bitrev3(lane&7).
__device__ __forceinline__ float wave_reduce8(float a[8], int lane) {
    {   // xor 1: 8 -> 4 values
        const bool hi = lane & 1;
#pragma unroll
        for (int j = 0; j < 4; ++j) {
            float send = hi ? a[j] : a[j + 4];
            float recv = __shfl_xor(send, 1, 64);
            float keep = hi ? a[j + 4] : a[j];
            a[j] = keep + recv;
        }
    }
    {   // xor 2: 4 -> 2
        const bool hi = lane & 2;
#pragma unroll
        for (int j = 0; j < 2; ++j) {
            float send = hi ? a[j] : a[j + 2];
            float recv = __shfl_xor(send, 2, 64);
            float keep = hi ? a[j + 2] : a[j];
            a[j] = keep + recv;
        }
    }
    {   // xor 4: 2 -> 1
        const bool hi = lane & 4;
        float send = hi ? a[0] : a[1];
        float recv = __shfl_xor(send, 4, 64);
        float keep = hi ? a[1] : a[0];
        a[0] = keep + recv;
    }
    float v = a[0];
    v += __shfl_xor(v, 8, 64);
    v += __shfl_xor(v, 16, 64);
    v += __shfl_xor(v, 32, 64);
    return v;
}

__device__ __forceinline__ void load_row(float4 dst[3], const float4* __restrict__ h4,
                                         int row, int lane) {
    const float4* hp = h4 + (size_t)row * D4 + lane;
#pragma unroll
    for (int c = 0; c < 3; ++c) dst[c] = hp[c * 64];
}

__global__ __launch_bounds__(BLOCK, 4)
void router_fused_kernel(const float* __restrict__ h,
                         const float* __restrict__ gate_w,
                         const float* __restrict__ gate_b,
                         float* __restrict__ out_idx,
                         float* __restrict__ out_w,
                         float* __restrict__ out_logits,
                         int B) {
    const int tid    = threadIdx.x;
    const int lane   = tid & 63;
    const int wave   = tid >> 6;
    const int gwave  = blockIdx.x * (BLOCK / 64) + wave;
    const int nwaves = gridDim.x * (BLOCK / 64);

    const int l3 = lane & 7;
    const int e_lane = ((l3 & 1) << 2) | (l3 & 2) | ((l3 >> 2) & 1);  // bitrev3
    const float bias = gate_b[e_lane];

    // Gate weights in LDS: [E][D4] float4 = 24 KB, loaded cooperatively once.
    // Lane reads gsh[e*D4 + c*64 + lane]: lane-consecutive 16 B -> conflict-free.
    __shared__ float4 gsh[E * D4];
    const float4* gw4 = (const float4*)gate_w;
#pragma unroll
    for (int i = 0; i < (E * D4) / BLOCK; ++i)
        gsh[i * BLOCK + tid] = gw4[i * BLOCK + tid];
    __syncthreads();

    const float4* h4 = (const float4*)h;

    int r = gwave;
    if (r >= B) return;

    float4 cv[3];
    load_row(cv, h4, r, lane);       // prime the pipeline

    while (true) {
        const int rn = r + nwaves;
        const bool more = (rn < B);            // wave-uniform branch

        float4 nv[3];
        if (more) load_row(nv, h4, rn, lane);  // in flight during compute

        float acc[E];
#pragma unroll
        for (int e = 0; e < E; ++e) acc[e] = 0.0f;

#pragma unroll
        for (int c = 0; c < 3; ++c) {
#pragma unroll
            for (int e = 0; e < E; ++e) {
                acc[e] = dot4acc(cv[c], gsh[e * D4 + c * 64 + lane], acc[e]);
            }
        }

        // Full 64-lane reduce: every lane gets expert e_lane's logit
        // (each 8-lane group holds the complete set of 8).
        float v = wave_reduce8(acc, lane) + bias;

        // Lanes 0..7 write the row's logits as one contiguous 32 B chunk.
        if (lane < 8) out_logits[(size_t)r * 8 + e_lane] = v;

        // Fused top-2 within the first 8-lane group (all groups redundantly
        // compute the same result). Comparator matches lax.top_k: strict >
        // on value, lower expert index wins ties.
        float t0 = v;          int x0 = e_lane;
        float t1 = -INFINITY;  int x1 = E;      // sentinel
#pragma unroll
        for (int m = 1; m <= 4; m <<= 1) {
            float w0 = __shfl_xor(t0, m, 64);
            int   j0 = __shfl_xor(x0, m, 64);
            float w1 = __shfl_xor(t1, m, 64);
            int   j1 = __shfl_xor(x1, m, 64);
            bool aFirst = (t0 > w0) || (t0 == w0 && x0 < j0);
            float f0  = aFirst ? t0 : w0;
            int   fi0 = aFirst ? x0 : j0;
            float losT = aFirst ? w0 : t0;   // loser's first
            int   losI = aFirst ? j0 : x0;
            float winT = aFirst ? t1 : w1;   // winner's second
            int   winI = aFirst ? x1 : j1;
            bool sWin = (winT > losT) || (winT == losT && winI < losI);
            float f1  = sWin ? winT : losT;
            int   fi1 = sWin ? winI : losI;
            t0 = f0; x0 = fi0; t1 = f1; x1 = fi1;
        }

        if (lane == 0) {
            float tt = expf(t1 - t0);
            float w0_ = 1.0f / (1.0f + tt);
            float w1_ = tt * w0_;
            ((float2*)out_idx)[r] = make_float2((float)x0, (float)x1);
            ((float2*)out_w)[r]   = make_float2(w0_, w1_);
        }

        if (!more) break;
#pragma unroll
        for (int i = 0; i < 3; ++i) cv[i] = nv[i];
        r = rn;
    }
}

extern "C" void kernel_launch(void* const* d_in, const int* in_sizes, int n_in,
                              void* d_out, int out_size, void* d_ws, size_t ws_size,
                              hipStream_t stream) {
    const float* h      = (const float*)d_in[0];
    const float* gate_w = (const float*)d_in[1];
    const float* gate_b = (const float*)d_in[2];

    const int B = in_sizes[0] / D;   // 32768

    float* out        = (float*)d_out;
    float* out_idx    = out;                       // [B,2] indices as float
    float* out_w      = out + (size_t)B * 2;       // [B,2] weights
    float* out_logits = out + (size_t)B * 4;       // [B,8] logits

    router_fused_kernel<<<dim3(GRID_A), dim3(BLOCK), 0, stream>>>(
        h, gate_w, gate_b, out_idx, out_w, out_logits, B);
}

// Round 6
// 180.151 us; speedup vs baseline: 1.1567x; 1.0403x over previous
//
#include <hip/hip_runtime.h>
#include <hip/hip_bf16.h>
#include <math.h>

// TopicRouter, single fused kernel:
//  logits[B,8] = h @ gate_w^T + b, plus per-row top-2 + softmax, one pass.
//  HBM-bound (96 MB of h).
//
//  R6: one row per wave + LDS gate + IN-PLACE rotating prefetch.
//  History: R4/R5 spilled (~150/75 MB scratch writes in WRITE_SIZE) because
//  the compiler targets the 64-VGPR occupancy granule and the explicit
//  prefetch buffer nv[3] (12 regs) didn't fit. Fix: after the FMA phase
//  consumes cv, reissue next row's loads INTO THE SAME cv registers (WAR on
//  issue order is safe; zero extra VGPRs), then run the ~400-800 cy
//  reduce + top-2 + output writes while the loads are in flight. Peak live
//  state ~40-50 regs -> genuinely fits 64, no spill at 8-waves/SIMD target.
//  Gate stays in 24 KB LDS (loaded once per block, lane-consecutive
//  conflict-free ds_read_b128); LDS caps residency at 6 blocks/CU =
//  24 waves/CU. In-flight bytes 24 waves x 3 KB >> BW*latency (~9 KB/CU),
//  so HBM should saturate (~6 TB/s vs R5's spill-bound 1.7).
//  Top-2 fused in-register after the wave reduce (lax.top_k tie semantics:
//  strict >, lower index wins ties).

constexpr int D  = 768;
constexpr int E  = 8;
constexpr int D4 = D / 4;          // 192 float4 per row
constexpr int BLOCK  = 256;        // 4 waves
constexpr int GRID_A = 1536;       // 6 blocks/CU (LDS-capped) x 256 CU

__device__ __forceinline__ float dot4acc(float4 a, float4 b, float acc) {
    acc = fmaf(a.x, b.x, acc);
    acc = fmaf(a.y, b.y, acc);
    acc = fmaf(a.z, b.z, acc);
    acc = fmaf(a.w, b.w, acc);
    return acc;
}

// Reduce a[8] (per-expert partials) across 64 lanes.
// Returns: this lane's total for expert e = bitrev3(lane&7).
__device__ __forceinline__ float wave_reduce8(float a[8], int lane) {
    {   // xor 1: 8 -> 4 values
        const bool hi = lane & 1;
#pragma unroll
        for (int j = 0; j < 4; ++j) {
            float send = hi ? a[j] : a[j + 4];
            float recv = __shfl_xor(send, 1, 64);
            float keep = hi ? a[j + 4] : a[j];
            a[j] = keep + recv;
        }
    }
    {   // xor 2: 4 -> 2
        const bool hi = lane & 2;
#pragma unroll
        for (int j = 0; j < 2; ++j) {
            float send = hi ? a[j] : a[j + 2];
            float recv = __shfl_xor(send, 2, 64);
            float keep = hi ? a[j + 2] : a[j];
            a[j] = keep + recv;
        }
    }
    {   // xor 4: 2 -> 1
        const bool hi = lane & 4;
        float send = hi ? a[0] : a[1];
        float recv = __shfl_xor(send, 4, 64);
        float keep = hi ? a[1] : a[0];
        a[0] = keep + recv;
    }
    float v = a[0];
    v += __shfl_xor(v, 8, 64);
    v += __shfl_xor(v, 16, 64);
    v += __shfl_xor(v, 32, 64);
    return v;
}

__global__ __launch_bounds__(BLOCK, 4)
void router_fused_kernel(const float* __restrict__ h,
                         const float* __restrict__ gate_w,
                         const float* __restrict__ gate_b,
                         float* __restrict__ out_idx,
                         float* __restrict__ out_w,
                         float* __restrict__ out_logits,
                         int B) {
    const int tid    = threadIdx.x;
    const int lane   = tid & 63;
    const int wave   = tid >> 6;
    const int gwave  = blockIdx.x * (BLOCK / 64) + wave;
    const int nwaves = gridDim.x * (BLOCK / 64);

    const int l3 = lane & 7;
    const int e_lane = ((l3 & 1) << 2) | (l3 & 2) | ((l3 >> 2) & 1);  // bitrev3
    const float bias = gate_b[e_lane];

    // Gate weights in LDS: [E][D4] float4 = 24 KB, loaded cooperatively once.
    // Lane reads gsh[e*D4 + c*64 + lane]: lane-consecutive 16 B -> conflict-free.
    __shared__ float4 gsh[E * D4];
    const float4* gw4 = (const float4*)gate_w;
#pragma unroll
    for (int i = 0; i < (E * D4) / BLOCK; ++i)
        gsh[i * BLOCK + tid] = gw4[i * BLOCK + tid];
    __syncthreads();

    const float4* h4 = (const float4*)h;

    int r = gwave;
    if (r >= B) return;

    // Prime: load row r into cv.
    float4 cv[3];
    {
        const float4* hp = h4 + (size_t)r * D4 + lane;
#pragma unroll
        for (int c = 0; c < 3; ++c) cv[c] = hp[c * 64];
    }

    while (true) {
        const int rn = r + nwaves;
        const bool more = (rn < B);            // wave-uniform branch

        // FMA phase: consume cv. After this, cv is dead.
        float acc[E];
#pragma unroll
        for (int e = 0; e < E; ++e) acc[e] = 0.0f;
#pragma unroll
        for (int c = 0; c < 3; ++c) {
#pragma unroll
            for (int e = 0; e < E; ++e) {
                acc[e] = dot4acc(cv[c], gsh[e * D4 + c * 64 + lane], acc[e]);
            }
        }

        // In-place prefetch: reload cv with next row NOW, so the loads fly
        // while the reduce/top-2/writes below execute (no extra registers).
        if (more) {
            const float4* hp = h4 + (size_t)rn * D4 + lane;
#pragma unroll
            for (int c = 0; c < 3; ++c) cv[c] = hp[c * 64];
        }

        // Full 64-lane reduce: every lane gets expert e_lane's logit.
        float v = wave_reduce8(acc, lane) + bias;

        // Lanes 0..7 write the row's logits as one contiguous 32 B chunk.
        if (lane < 8) out_logits[(size_t)r * 8 + e_lane] = v;

        // Fused top-2 (all 8-lane groups compute the same result).
        // Comparator matches lax.top_k: strict >, lower index wins ties.
        float t0 = v;          int x0 = e_lane;
        float t1 = -INFINITY;  int x1 = E;      // sentinel
#pragma unroll
        for (int m = 1; m <= 4; m <<= 1) {
            float w0 = __shfl_xor(t0, m, 64);
            int   j0 = __shfl_xor(x0, m, 64);
            float w1 = __shfl_xor(t1, m, 64);
            int   j1 = __shfl_xor(x1, m, 64);
            bool aFirst = (t0 > w0) || (t0 == w0 && x0 < j0);
            float f0  = aFirst ? t0 : w0;
            int   fi0 = aFirst ? x0 : j0;
            float losT = aFirst ? w0 : t0;   // loser's first
            int   losI = aFirst ? j0 : x0;
            float winT = aFirst ? t1 : w1;   // winner's second
            int   winI = aFirst ? x1 : j1;
            bool sWin = (winT > losT) || (winT == losT && winI < losI);
            float f1  = sWin ? winT : losT;
            int   fi1 = sWin ? winI : losI;
            t0 = f0; x0 = fi0; t1 = f1; x1 = fi1;
        }

        if (lane == 0) {
            float tt = expf(t1 - t0);
            float w0_ = 1.0f / (1.0f + tt);
            float w1_ = tt * w0_;
            ((float2*)out_idx)[r] = make_float2((float)x0, (float)x1);
            ((float2*)out_w)[r]   = make_float2(w0_, w1_);
        }

        if (!more) break;
        r = rn;
    }
}

extern "C" void kernel_launch(void* const* d_in, const int* in_sizes, int n_in,
                              void* d_out, int out_size, void* d_ws, size_t ws_size,
                              hipStream_t stream) {
    const float* h      = (const float*)d_in[0];
    const float* gate_w = (const float*)d_in[1];
    const float* gate_b = (const float*)d_in[2];

    const int B = in_sizes[0] / D;   // 32768

    float* out        = (float*)d_out;
    float* out_idx    = out;                       // [B,2] indices as float
    float* out_w      = out + (size_t)B * 2;       // [B,2] weights
    float* out_logits = out + (size_t)B * 4;       // [B,8] logits

    router_fused_kernel<<<dim3(GRID_A), dim3(BLOCK), 0, stream>>>(
        h, gate_w, gate_b, out_idx, out_w, out_logits, B);
}

// Round 7
// 147.180 us; speedup vs baseline: 1.4158x; 1.2240x over previous
//
#include <hip/hip_runtime.h>
#include <hip/hip_bf16.h>
#include <math.h>

// TopicRouter, single fused kernel:
//  logits[B,8] = h @ gate_w^T + b, plus per-row top-2 + softmax, one pass.
//  HBM-bound (96 MB of h).
//
//  R7: one row per wave + LDS gate + in-place prefetch + (256,2) bounds.
//  Spill history: with __launch_bounds__(256,4) the allocator pins the
//  kernel at the 64-VGPR/8-wave granule and spills ~5 regs per iteration
//  (R4: 150 MB, R5: 75 MB, R6: 38 MB scratch writes in WRITE_SIZE); the
//  ~900-cy scratch round-trips serialize every iteration, so more TLP made
//  it SLOWER than the old 2-wave register-gate version. Fix: (256,2) gives
//  a 256-reg budget -> ~90 used -> spill impossible. Occupancy then comes
//  from actual usage (~5 waves/SIMD VGPR cap, 6 blocks/CU LDS cap ->
//  ~16-20 waves/CU), still 2-2.5x the original session's TLP. At that TLP,
//  no deep pipeline is needed to saturate HBM (per-CU pull ~19 TB/s-equiv
//  without prefetch); the in-place prefetch (reload cv right after the FMA
//  phase, zero extra regs) is kept as free overlap.
//  Gate: 24 KB LDS, loaded once per block, lane-consecutive conflict-free
//  ds_read_b128. Top-2 fused in-register after the wave reduce (lax.top_k
//  tie semantics: strict >, lower index wins ties).

constexpr int D  = 768;
constexpr int E  = 8;
constexpr int D4 = D / 4;          // 192 float4 per row
constexpr int BLOCK  = 256;        // 4 waves
constexpr int GRID_A = 1536;       // 6 blocks/CU (LDS-capped) x 256 CU

__device__ __forceinline__ float dot4acc(float4 a, float4 b, float acc) {
    acc = fmaf(a.x, b.x, acc);
    acc = fmaf(a.y, b.y, acc);
    acc = fmaf(a.z, b.z, acc);
    acc = fmaf(a.w, b.w, acc);
    return acc;
}

// Reduce a[8] (per-expert partials) across 64 lanes.
// Returns: this lane's total for expert e = bitrev3(lane&7).
__device__ __forceinline__ float wave_reduce8(float a[8], int lane) {
    {   // xor 1: 8 -> 4 values
        const bool hi = lane & 1;
#pragma unroll
        for (int j = 0; j < 4; ++j) {
            float send = hi ? a[j] : a[j + 4];
            float recv = __shfl_xor(send, 1, 64);
            float keep = hi ? a[j + 4] : a[j];
            a[j] = keep + recv;
        }
    }
    {   // xor 2: 4 -> 2
        const bool hi = lane & 2;
#pragma unroll
        for (int j = 0; j < 2; ++j) {
            float send = hi ? a[j] : a[j + 2];
            float recv = __shfl_xor(send, 2, 64);
            float keep = hi ? a[j + 2] : a[j];
            a[j] = keep + recv;
        }
    }
    {   // xor 4: 2 -> 1
        const bool hi = lane & 4;
        float send = hi ? a[0] : a[1];
        float recv = __shfl_xor(send, 4, 64);
        float keep = hi ? a[1] : a[0];
        a[0] = keep + recv;
    }
    float v = a[0];
    v += __shfl_xor(v, 8, 64);
    v += __shfl_xor(v, 16, 64);
    v += __shfl_xor(v, 32, 64);
    return v;
}

__global__ __launch_bounds__(BLOCK, 2)
void router_fused_kernel(const float* __restrict__ h,
                         const float* __restrict__ gate_w,
                         const float* __restrict__ gate_b,
                         float* __restrict__ out_idx,
                         float* __restrict__ out_w,
                         float* __restrict__ out_logits,
                         int B) {
    const int tid    = threadIdx.x;
    const int lane   = tid & 63;
    const int wave   = tid >> 6;
    const int gwave  = blockIdx.x * (BLOCK / 64) + wave;
    const int nwaves = gridDim.x * (BLOCK / 64);

    const int l3 = lane & 7;
    const int e_lane = ((l3 & 1) << 2) | (l3 & 2) | ((l3 >> 2) & 1);  // bitrev3
    const float bias = gate_b[e_lane];

    // Gate weights in LDS: [E][D4] float4 = 24 KB, loaded cooperatively once.
    // Lane reads gsh[e*D4 + c*64 + lane]: lane-consecutive 16 B -> conflict-free.
    __shared__ float4 gsh[E * D4];
    const float4* gw4 = (const float4*)gate_w;
#pragma unroll
    for (int i = 0; i < (E * D4) / BLOCK; ++i)
        gsh[i * BLOCK + tid] = gw4[i * BLOCK + tid];
    __syncthreads();

    const float4* h4 = (const float4*)h;

    int r = gwave;
    if (r >= B) return;

    // Prime: load row r into cv.
    float4 cv[3];
    {
        const float4* hp = h4 + (size_t)r * D4 + lane;
#pragma unroll
        for (int c = 0; c < 3; ++c) cv[c] = hp[c * 64];
    }

    while (true) {
        const int rn = r + nwaves;
        const bool more = (rn < B);            // wave-uniform branch

        // FMA phase: consume cv. After this, cv is dead.
        float acc[E];
#pragma unroll
        for (int e = 0; e < E; ++e) acc[e] = 0.0f;
#pragma unroll
        for (int c = 0; c < 3; ++c) {
#pragma unroll
            for (int e = 0; e < E; ++e) {
                acc[e] = dot4acc(cv[c], gsh[e * D4 + c * 64 + lane], acc[e]);
            }
        }

        // In-place prefetch: reload cv with next row NOW, so the loads fly
        // while the reduce/top-2/writes below execute (no extra registers).
        if (more) {
            const float4* hp = h4 + (size_t)rn * D4 + lane;
#pragma unroll
            for (int c = 0; c < 3; ++c) cv[c] = hp[c * 64];
        }

        // Full 64-lane reduce: every lane gets expert e_lane's logit.
        float v = wave_reduce8(acc, lane) + bias;

        // Lanes 0..7 write the row's logits as one contiguous 32 B chunk.
        if (lane < 8) out_logits[(size_t)r * 8 + e_lane] = v;

        // Fused top-2 (all 8-lane groups compute the same result).
        // Comparator matches lax.top_k: strict >, lower index wins ties.
        float t0 = v;          int x0 = e_lane;
        float t1 = -INFINITY;  int x1 = E;      // sentinel
#pragma unroll
        for (int m = 1; m <= 4; m <<= 1) {
            float w0 = __shfl_xor(t0, m, 64);
            int   j0 = __shfl_xor(x0, m, 64);
            float w1 = __shfl_xor(t1, m, 64);
            int   j1 = __shfl_xor(x1, m, 64);
            bool aFirst = (t0 > w0) || (t0 == w0 && x0 < j0);
            float f0  = aFirst ? t0 : w0;
            int   fi0 = aFirst ? x0 : j0;
            float losT = aFirst ? w0 : t0;   // loser's first
            int   losI = aFirst ? j0 : x0;
            float winT = aFirst ? t1 : w1;   // winner's second
            int   winI = aFirst ? x1 : j1;
            bool sWin = (winT > losT) || (winT == losT && winI < losI);
            float f1  = sWin ? winT : losT;
            int   fi1 = sWin ? winI : losI;
            t0 = f0; x0 = fi0; t1 = f1; x1 = fi1;
        }

        if (lane == 0) {
            float tt = expf(t1 - t0);
            float w0_ = 1.0f / (1.0f + tt);
            float w1_ = tt * w0_;
            ((float2*)out_idx)[r] = make_float2((float)x0, (float)x1);
            ((float2*)out_w)[r]   = make_float2(w0_, w1_);
        }

        if (!more) break;
        r = rn;
    }
}

extern "C" void kernel_launch(void* const* d_in, const int* in_sizes, int n_in,
                              void* d_out, int out_size, void* d_ws, size_t ws_size,
                              hipStream_t stream) {
    const float* h      = (const float*)d_in[0];
    const float* gate_w = (const float*)d_in[1];
    const float* gate_b = (const float*)d_in[2];

    const int B = in_sizes[0] / D;   // 32768

    float* out        = (float*)d_out;
    float* out_idx    = out;                       // [B,2] indices as float
    float* out_w      = out + (size_t)B * 2;       // [B,2] weights
    float* out_logits = out + (size_t)B * 4;       // [B,8] logits

    router_fused_kernel<<<dim3(GRID_A), dim3(BLOCK), 0, stream>>>(
        h, gate_w, gate_b, out_idx, out_w, out_logits, B);
}